// Round 1
// baseline (2399.551 us; speedup 1.0000x reference)
//
#include <hip/hip_runtime.h>
#include <hip/hip_bf16.h>

// GCN encoder: 3 layers on N=100000 nodes, E=1250000 edges, 64 features.
// out = dense3( gcn2( gcn1(x) ) ), gcn(x) = relu(D^-1/2 (A+I) D^-1/2 (xW) + b)
// Folding: hs = dinv .* (xW);  out[d] = relu(dinv[d]*(hs[d] + sum_{s->d} hs[s]) + b)

#define WG 256

__global__ __launch_bounds__(WG) void deg_init(float* __restrict__ deg, int N) {
    int i = blockIdx.x * WG + threadIdx.x;
    if (i < N) deg[i] = 1.0f;   // self-loop
}

__global__ __launch_bounds__(WG) void deg_count(const int* __restrict__ ei,
                                                float* __restrict__ deg, int E) {
    int e = blockIdx.x * WG + threadIdx.x;
    if (e < E) {
        int d = ei[E + e];      // dst row of edge_index
        unsafeAtomicAdd(&deg[d], 1.0f);
    }
}

__global__ __launch_bounds__(WG) void deg_rsqrt(const float* __restrict__ deg,
                                                float* __restrict__ dinv, int N) {
    int i = blockIdx.x * WG + threadIdx.x;
    if (i < N) dinv[i] = rsqrtf(deg[i]);
}

// Fused GEMM: out = post( pre(in) @ W )
//   pre(v)  = pre_flag ? relu(dinv[row]*v + b_pre[col]) : v
//   post(a) = (post_scale ? dinv[row]*a : a) + (b_post ? b_post[col] : 0)
// Writes out1 and (if non-null) out2 (identical copy, used as scatter accumulator init).
// 64 rows per block, 256 threads, 4x4 register tile per thread.
__global__ __launch_bounds__(WG) void gemm_fused(
    const float* __restrict__ in, const float* __restrict__ W,
    const float* __restrict__ dinv, const float* __restrict__ b_pre, int pre_flag,
    int post_scale, const float* __restrict__ b_post,
    float* __restrict__ out1, float* __restrict__ out2, int n_rows)
{
    __shared__ float Ws[64 * 64];
    __shared__ float xs[64 * 65];   // +1 pad: conflict-free row-broadcast reads

    const int t = threadIdx.x;
    const int row0 = blockIdx.x * 64;

    // Stage W (same layout, 16KB) via float4
    const float4* W4 = (const float4*)W;
    float4* Ws4 = (float4*)Ws;
#pragma unroll
    for (int i = 0; i < 4; i++) Ws4[i * WG + t] = W4[i * WG + t];

    // Stage x tile with fused pre-transform
#pragma unroll
    for (int i = 0; i < 4; i++) {
        int j = i * WG + t;              // j in [0,1024): float4 slot
        int rr = j >> 4;                 // local row
        int c  = (j & 15) * 4;           // col
        int row = row0 + rr;
        float4 v = make_float4(0.f, 0.f, 0.f, 0.f);
        if (row < n_rows) {
            v = *(const float4*)(in + (size_t)row * 64 + c);
            if (pre_flag) {
                float dv = dinv[row];
                float4 bb = *(const float4*)(b_pre + c);
                v.x = fmaxf(fmaf(dv, v.x, bb.x), 0.f);
                v.y = fmaxf(fmaf(dv, v.y, bb.y), 0.f);
                v.z = fmaxf(fmaf(dv, v.z, bb.z), 0.f);
                v.w = fmaxf(fmaf(dv, v.w, bb.w), 0.f);
            }
        }
        float* xp = xs + rr * 65 + c;
        xp[0] = v.x; xp[1] = v.y; xp[2] = v.z; xp[3] = v.w;
    }
    __syncthreads();

    const int fg = (t & 15) * 4;        // feature group base
    const int r0 = (t >> 4) * 4;        // row group base
    float acc[4][4] = {};

#pragma unroll
    for (int k = 0; k < 64; k++) {
        float4 wv = *(const float4*)(Ws + k * 64 + fg);   // 2-way aliasing = free
#pragma unroll
        for (int r = 0; r < 4; r++) {
            float xr = xs[(r0 + r) * 65 + k];             // 4 distinct banks, broadcast
            acc[r][0] = fmaf(xr, wv.x, acc[r][0]);
            acc[r][1] = fmaf(xr, wv.y, acc[r][1]);
            acc[r][2] = fmaf(xr, wv.z, acc[r][2]);
            acc[r][3] = fmaf(xr, wv.w, acc[r][3]);
        }
    }

    float4 bp = b_post ? *(const float4*)(b_post + fg) : make_float4(0.f, 0.f, 0.f, 0.f);
#pragma unroll
    for (int r = 0; r < 4; r++) {
        int row = row0 + r0 + r;
        if (row >= n_rows) break;
        float sc = post_scale ? dinv[row] : 1.0f;
        float4 o;
        o.x = fmaf(acc[r][0], sc, bp.x);
        o.y = fmaf(acc[r][1], sc, bp.y);
        o.z = fmaf(acc[r][2], sc, bp.z);
        o.w = fmaf(acc[r][3], sc, bp.w);
        *(float4*)(out1 + (size_t)row * 64 + fg) = o;
        if (out2) *(float4*)(out2 + (size_t)row * 64 + fg) = o;
    }
}

// Edge scatter: acc[dst] += hs[src].  16 threads per edge, float4 per thread.
__global__ __launch_bounds__(WG) void scatter_edges(
    const float* __restrict__ hs, float* __restrict__ acc,
    const int* __restrict__ ei, int E)
{
    long long gid = (long long)blockIdx.x * WG + threadIdx.x;
    int e = (int)(gid >> 4);
    if (e >= E) return;
    int l = (int)(gid & 15);
    int s = ei[e];
    int d = ei[(size_t)E + e];
    float4 v = *(const float4*)(hs + (size_t)s * 64 + l * 4);
    float* a = acc + (size_t)d * 64 + l * 4;
    unsafeAtomicAdd(a + 0, v.x);
    unsafeAtomicAdd(a + 1, v.y);
    unsafeAtomicAdd(a + 2, v.z);
    unsafeAtomicAdd(a + 3, v.w);
}

extern "C" void kernel_launch(void* const* d_in, const int* in_sizes, int n_in,
                              void* d_out, int out_size, void* d_ws, size_t ws_size,
                              hipStream_t stream) {
    const float* x  = (const float*)d_in[0];
    const int*   ei = (const int*)d_in[1];      // edge_index as int32 per harness
    const float* W1 = (const float*)d_in[2];
    const float* b1 = (const float*)d_in[3];
    const float* W2 = (const float*)d_in[4];
    const float* b2 = (const float*)d_in[5];
    const float* W3 = (const float*)d_in[6];
    const float* b3 = (const float*)d_in[7];
    float* out = (float*)d_out;

    const int N = in_sizes[0] / 64;    // 100000
    const int E = in_sizes[1] / 2;     // 1250000

    float* deg  = (float*)d_ws;
    float* dinv = deg + N;
    float* A    = dinv + N;            // hs buffer  (N*64 floats)
    float* B    = A + (size_t)N * 64;  // acc buffer (N*64 floats)

    const int gN = (N + WG - 1) / WG;
    const int gE = (E + WG - 1) / WG;
    const int gG = (N + 63) / 64;
    const int gS = (int)(((long long)E * 16 + WG - 1) / WG);

    deg_init <<<gN, WG, 0, stream>>>(deg, N);
    deg_count<<<gE, WG, 0, stream>>>(ei, deg, E);
    deg_rsqrt<<<gN, WG, 0, stream>>>(deg, dinv, N);

    // Layer 1: hs1 -> A, acc1 -> B
    gemm_fused<<<gG, WG, 0, stream>>>(x, W1, dinv, nullptr, 0, 1, nullptr, A, B, N);
    scatter_edges<<<gS, WG, 0, stream>>>(A, B, ei, E);

    // Layer 2: in = B (pre: relu(dinv*v + b1)), hs2 -> A, acc2 -> B (in-place ok)
    gemm_fused<<<gG, WG, 0, stream>>>(B, W2, dinv, b1, 1, 1, nullptr, A, B, N);
    scatter_edges<<<gS, WG, 0, stream>>>(A, B, ei, E);

    // Layer 3: in = B (pre: relu(dinv*v + b2)), plain dense + b3 -> out
    gemm_fused<<<gG, WG, 0, stream>>>(B, W3, dinv, b2, 1, 0, b3, out, nullptr, N);
}

// Round 2
// 740.338 us; speedup vs baseline: 3.2412x; 3.2412x over previous
//
#include <hip/hip_runtime.h>
#include <hip/hip_bf16.h>

// GCN encoder: 3 layers on N=100000 nodes, E=1250000 edges, 64 features.
// gcn(x) = relu(D^-1/2 (A+I) D^-1/2 (xW) + b)
// Folding: hs = dinv .* (xW);  agg[d] = hs[d] + sum_{s->d} hs[s];
//          next layer's GEMM applies relu(dinv[d]*agg + b) as its pre-transform.
// R1: replaced 80M-fp32-atomic scatter with device-built dst-CSR + gather
//     segmented reduction (wave per node, lane per feature).

#define WG 256

__global__ __launch_bounds__(WG) void hist_init(int* __restrict__ hist, int N) {
    int i = blockIdx.x * WG + threadIdx.x;
    if (i < N) hist[i] = 0;
}

__global__ __launch_bounds__(WG) void hist_count(const int* __restrict__ ei,
                                                 int* __restrict__ hist, int E) {
    int e = blockIdx.x * WG + threadIdx.x;
    if (e < E) atomicAdd(&hist[ei[E + e]], 1);   // dst row
}

__global__ __launch_bounds__(WG) void deg_rsqrt(const int* __restrict__ hist,
                                                float* __restrict__ dinv, int N) {
    int i = blockIdx.x * WG + threadIdx.x;
    if (i < N) dinv[i] = rsqrtf((float)(hist[i] + 1));   // +1 self-loop
}

// Single-block exclusive scan of hist[N] -> off[N+1]; also rewrites hist[i] := off[i]
// so the same buffer serves as the fill cursor.  N=100k, 1024 threads x ~98 elems.
__global__ __launch_bounds__(1024) void scan_offsets(int* __restrict__ hist,
                                                     int* __restrict__ off, int N) {
    __shared__ int partial[1024];
    const int t = threadIdx.x;
    const int chunk = (N + 1023) / 1024;
    const int base = t * chunk;

    int sum = 0;
    for (int i = 0; i < chunk; i++) {
        int idx = base + i;
        if (idx < N) sum += hist[idx];
    }
    partial[t] = sum;
    __syncthreads();
    // Hillis-Steele inclusive scan over 1024 partials
    for (int ofs = 1; ofs < 1024; ofs <<= 1) {
        int v = (t >= ofs) ? partial[t - ofs] : 0;
        __syncthreads();
        partial[t] += v;
        __syncthreads();
    }
    int run = partial[t] - sum;          // exclusive prefix of this chunk
    for (int i = 0; i < chunk; i++) {
        int idx = base + i;
        if (idx < N) {
            int h = hist[idx];
            off[idx] = run;
            hist[idx] = run;             // cursor init
            run += h;
        }
    }
    if (t == 1023) off[N] = partial[1023];
}

__global__ __launch_bounds__(WG) void csr_fill(const int* __restrict__ ei,
                                               int* __restrict__ cursor,
                                               int* __restrict__ csr, int E) {
    int e = blockIdx.x * WG + threadIdx.x;
    if (e < E) {
        int s = ei[e];
        int d = ei[E + e];
        int pos = atomicAdd(&cursor[d], 1);
        csr[pos] = s;
    }
}

// Fused GEMM: out = post( pre(in) @ W )
//   pre(v)  = pre_flag ? relu(dinv[row]*v + b_pre[col]) : v
//   post(a) = (post_scale ? dinv[row]*a : a) + (b_post ? b_post[col] : 0)
// 64 rows per block, 256 threads, 4x4 register tile per thread.
__global__ __launch_bounds__(WG) void gemm_fused(
    const float* __restrict__ in, const float* __restrict__ W,
    const float* __restrict__ dinv, const float* __restrict__ b_pre, int pre_flag,
    int post_scale, const float* __restrict__ b_post,
    float* __restrict__ out1, int n_rows)
{
    __shared__ float Ws[64 * 64];
    __shared__ float xs[64 * 65];   // +1 pad: conflict-free row-broadcast reads

    const int t = threadIdx.x;
    const int row0 = blockIdx.x * 64;

    const float4* W4 = (const float4*)W;
    float4* Ws4 = (float4*)Ws;
#pragma unroll
    for (int i = 0; i < 4; i++) Ws4[i * WG + t] = W4[i * WG + t];

#pragma unroll
    for (int i = 0; i < 4; i++) {
        int j = i * WG + t;              // float4 slot
        int rr = j >> 4;                 // local row
        int c  = (j & 15) * 4;           // col
        int row = row0 + rr;
        float4 v = make_float4(0.f, 0.f, 0.f, 0.f);
        if (row < n_rows) {
            v = *(const float4*)(in + (size_t)row * 64 + c);
            if (pre_flag) {
                float dv = dinv[row];
                float4 bb = *(const float4*)(b_pre + c);
                v.x = fmaxf(fmaf(dv, v.x, bb.x), 0.f);
                v.y = fmaxf(fmaf(dv, v.y, bb.y), 0.f);
                v.z = fmaxf(fmaf(dv, v.z, bb.z), 0.f);
                v.w = fmaxf(fmaf(dv, v.w, bb.w), 0.f);
            }
        }
        float* xp = xs + rr * 65 + c;
        xp[0] = v.x; xp[1] = v.y; xp[2] = v.z; xp[3] = v.w;
    }
    __syncthreads();

    const int fg = (t & 15) * 4;
    const int r0 = (t >> 4) * 4;
    float acc[4][4] = {};

#pragma unroll
    for (int k = 0; k < 64; k++) {
        float4 wv = *(const float4*)(Ws + k * 64 + fg);
#pragma unroll
        for (int r = 0; r < 4; r++) {
            float xr = xs[(r0 + r) * 65 + k];
            acc[r][0] = fmaf(xr, wv.x, acc[r][0]);
            acc[r][1] = fmaf(xr, wv.y, acc[r][1]);
            acc[r][2] = fmaf(xr, wv.z, acc[r][2]);
            acc[r][3] = fmaf(xr, wv.w, acc[r][3]);
        }
    }

    float4 bp = b_post ? *(const float4*)(b_post + fg) : make_float4(0.f, 0.f, 0.f, 0.f);
#pragma unroll
    for (int r = 0; r < 4; r++) {
        int row = row0 + r0 + r;
        if (row >= n_rows) break;
        float sc = post_scale ? dinv[row] : 1.0f;
        float4 o;
        o.x = fmaf(acc[r][0], sc, bp.x);
        o.y = fmaf(acc[r][1], sc, bp.y);
        o.z = fmaf(acc[r][2], sc, bp.z);
        o.w = fmaf(acc[r][3], sc, bp.w);
        *(float4*)(out1 + (size_t)row * 64 + fg) = o;
    }
}

// Segmented reduction over dst-CSR: B[d] = A[d] + sum_{e in [off[d],off[d+1])} A[csr[e]]
// One 64-lane wave per node, lane = feature; 4 nodes per 256-thread block.
__global__ __launch_bounds__(WG) void aggregate(
    const float* __restrict__ A, float* __restrict__ B,
    const int* __restrict__ off, const int* __restrict__ csr, int N)
{
    int node = blockIdx.x * 4 + (threadIdx.x >> 6);
    if (node >= N) return;
    int lane = threadIdx.x & 63;

    int s0 = off[node];
    int s1 = off[node + 1];
    float acc = A[(size_t)node * 64 + lane];   // self-loop

    int e = s0;
    for (; e + 4 <= s1; e += 4) {              // 4-edge ILP
        int i0 = csr[e], i1 = csr[e + 1], i2 = csr[e + 2], i3 = csr[e + 3];
        float v0 = A[(size_t)i0 * 64 + lane];
        float v1 = A[(size_t)i1 * 64 + lane];
        float v2 = A[(size_t)i2 * 64 + lane];
        float v3 = A[(size_t)i3 * 64 + lane];
        acc += (v0 + v1) + (v2 + v3);
    }
    for (; e < s1; e++)
        acc += A[(size_t)csr[e] * 64 + lane];

    B[(size_t)node * 64 + lane] = acc;
}

extern "C" void kernel_launch(void* const* d_in, const int* in_sizes, int n_in,
                              void* d_out, int out_size, void* d_ws, size_t ws_size,
                              hipStream_t stream) {
    const float* x  = (const float*)d_in[0];
    const int*   ei = (const int*)d_in[1];
    const float* W1 = (const float*)d_in[2];
    const float* b1 = (const float*)d_in[3];
    const float* W2 = (const float*)d_in[4];
    const float* b2 = (const float*)d_in[5];
    const float* W3 = (const float*)d_in[6];
    const float* b3 = (const float*)d_in[7];
    float* out = (float*)d_out;

    const int N = in_sizes[0] / 64;    // 100000
    const int E = in_sizes[1] / 2;     // 1250000

    // workspace layout
    int*   hist = (int*)d_ws;                       // N ints (later: cursor)
    int*   off  = hist + N;                         // N+1 ints
    int*   csr  = off + (N + 1);                    // E ints
    float* dinv = (float*)(csr + E);                // N floats
    float* A    = dinv + N;                         // N*64 floats (hs)
    float* B    = A + (size_t)N * 64;               // N*64 floats (agg)

    const int gN = (N + WG - 1) / WG;
    const int gE = (E + WG - 1) / WG;
    const int gG = (N + 63) / 64;
    const int gA = (N + 3) / 4;

    // CSR build (per call; ws is re-poisoned every launch)
    hist_init   <<<gN, WG, 0, stream>>>(hist, N);
    hist_count  <<<gE, WG, 0, stream>>>(ei, hist, E);
    deg_rsqrt   <<<gN, WG, 0, stream>>>(hist, dinv, N);
    scan_offsets<<<1, 1024, 0, stream>>>(hist, off, N);
    csr_fill    <<<gE, WG, 0, stream>>>(ei, hist, csr, E);

    // Layer 1: A = dinv.*(x@W1); B = A[d] + sum A[src]
    gemm_fused<<<gG, WG, 0, stream>>>(x, W1, dinv, nullptr, 0, 1, nullptr, A, N);
    aggregate <<<gA, WG, 0, stream>>>(A, B, off, csr, N);

    // Layer 2: in = B (pre: relu(dinv*v + b1)); A = dinv.*(h@W2); B = agg
    gemm_fused<<<gG, WG, 0, stream>>>(B, W2, dinv, b1, 1, 1, nullptr, A, N);
    aggregate <<<gA, WG, 0, stream>>>(A, B, off, csr, N);

    // Layer 3: in = B (pre: relu(dinv*v + b2)); out = h@W3 + b3
    gemm_fused<<<gG, WG, 0, stream>>>(B, W3, dinv, b2, 1, 0, b3, out, N);
}

// Round 3
// 491.996 us; speedup vs baseline: 4.8772x; 1.5048x over previous
//
#include <hip/hip_runtime.h>
#include <hip/hip_bf16.h>

// GCN encoder: 3 layers on N=100000 nodes, E=1250000 edges, 64 features.
// gcn(x) = relu(D^-1/2 (A+I) D^-1/2 (xW) + b)
// Folding: hs = dinv .* (xW);  agg[d] = hs[d] + sum_{s->d} hs[s];
//          next layer's GEMM applies relu(dinv[d]*agg + b) as its pre-transform.
// R1: dst-CSR + gather segmented reduction (no fp32 atomics).
// R2: single-block scan was 258us (1 CU!) -> 3-phase hierarchical scan.

#define WG 256

__global__ __launch_bounds__(WG) void hist_init(int* __restrict__ hist, int N) {
    int i = blockIdx.x * WG + threadIdx.x;
    if (i < N) hist[i] = 0;
}

__global__ __launch_bounds__(WG) void hist_count(const int* __restrict__ ei,
                                                 int* __restrict__ hist, int E) {
    int e = blockIdx.x * WG + threadIdx.x;
    if (e < E) atomicAdd(&hist[ei[E + e]], 1);   // dst row
}

__global__ __launch_bounds__(WG) void deg_rsqrt(const int* __restrict__ hist,
                                                float* __restrict__ dinv, int N) {
    int i = blockIdx.x * WG + threadIdx.x;
    if (i < N) dinv[i] = rsqrtf((float)(hist[i] + 1));   // +1 self-loop
}

// ---- 3-phase exclusive scan of hist[N] -> off[N+1] (+ cursor init) ----
// Phase 1: each block scans a 1024-elem chunk (4/thread), writes local-exclusive
// prefixes into off[] and its chunk total into blk_sums[b].
__global__ __launch_bounds__(WG) void scan_p1(const int* __restrict__ hist,
                                              int* __restrict__ off,
                                              int* __restrict__ blk_sums, int N) {
    __shared__ int sums[WG];
    const int t = threadIdx.x;
    const int base = blockIdx.x * 1024 + t * 4;
    int v[4];
    int s = 0;
#pragma unroll
    for (int i = 0; i < 4; i++) {
        int idx = base + i;
        v[i] = (idx < N) ? hist[idx] : 0;
        s += v[i];
    }
    sums[t] = s;
    __syncthreads();
    for (int ofs = 1; ofs < WG; ofs <<= 1) {
        int u = (t >= ofs) ? sums[t - ofs] : 0;
        __syncthreads();
        sums[t] += u;
        __syncthreads();
    }
    int run = sums[t] - s;               // thread's exclusive prefix in block
#pragma unroll
    for (int i = 0; i < 4; i++) {
        int idx = base + i;
        if (idx < N) off[idx] = run;
        run += v[i];
    }
    if (t == WG - 1) blk_sums[blockIdx.x] = sums[WG - 1];
}

// Phase 2: single tiny block scans blk_sums (nb <= 256) to exclusive prefixes;
// writes grand total to off[N].
__global__ __launch_bounds__(WG) void scan_p2(int* __restrict__ blk_sums, int nb,
                                              int* __restrict__ off, int N) {
    __shared__ int sums[WG];
    const int t = threadIdx.x;
    int s = (t < nb) ? blk_sums[t] : 0;
    sums[t] = s;
    __syncthreads();
    for (int ofs = 1; ofs < WG; ofs <<= 1) {
        int u = (t >= ofs) ? sums[t - ofs] : 0;
        __syncthreads();
        sums[t] += u;
        __syncthreads();
    }
    if (t < nb) blk_sums[t] = sums[t] - s;   // exclusive
    if (t == WG - 1) off[N] = sums[WG - 1];
}

// Phase 3: off[i] += blk_prefix; cursor[i] = off[i].
__global__ __launch_bounds__(WG) void scan_p3(int* __restrict__ off,
                                              const int* __restrict__ blk_sums,
                                              int* __restrict__ cursor, int N) {
    int i = blockIdx.x * WG + threadIdx.x;
    if (i < N) {
        int v = off[i] + blk_sums[i >> 10];
        off[i] = v;
        cursor[i] = v;
    }
}

__global__ __launch_bounds__(WG) void csr_fill(const int* __restrict__ ei,
                                               int* __restrict__ cursor,
                                               int* __restrict__ csr, int E) {
    int e = blockIdx.x * WG + threadIdx.x;
    if (e < E) {
        int s = ei[e];
        int d = ei[E + e];
        int pos = atomicAdd(&cursor[d], 1);
        csr[pos] = s;
    }
}

// Fused GEMM: out = post( pre(in) @ W )
//   pre(v)  = pre_flag ? relu(dinv[row]*v + b_pre[col]) : v
//   post(a) = (post_scale ? dinv[row]*a : a) + (b_post ? b_post[col] : 0)
// 64 rows per block, 256 threads, 4x4 register tile per thread.
__global__ __launch_bounds__(WG) void gemm_fused(
    const float* __restrict__ in, const float* __restrict__ W,
    const float* __restrict__ dinv, const float* __restrict__ b_pre, int pre_flag,
    int post_scale, const float* __restrict__ b_post,
    float* __restrict__ out1, int n_rows)
{
    __shared__ float Ws[64 * 64];
    __shared__ float xs[64 * 65];   // +1 pad: conflict-free row-broadcast reads

    const int t = threadIdx.x;
    const int row0 = blockIdx.x * 64;

    const float4* W4 = (const float4*)W;
    float4* Ws4 = (float4*)Ws;
#pragma unroll
    for (int i = 0; i < 4; i++) Ws4[i * WG + t] = W4[i * WG + t];

#pragma unroll
    for (int i = 0; i < 4; i++) {
        int j = i * WG + t;              // float4 slot
        int rr = j >> 4;                 // local row
        int c  = (j & 15) * 4;           // col
        int row = row0 + rr;
        float4 v = make_float4(0.f, 0.f, 0.f, 0.f);
        if (row < n_rows) {
            v = *(const float4*)(in + (size_t)row * 64 + c);
            if (pre_flag) {
                float dv = dinv[row];
                float4 bb = *(const float4*)(b_pre + c);
                v.x = fmaxf(fmaf(dv, v.x, bb.x), 0.f);
                v.y = fmaxf(fmaf(dv, v.y, bb.y), 0.f);
                v.z = fmaxf(fmaf(dv, v.z, bb.z), 0.f);
                v.w = fmaxf(fmaf(dv, v.w, bb.w), 0.f);
            }
        }
        float* xp = xs + rr * 65 + c;
        xp[0] = v.x; xp[1] = v.y; xp[2] = v.z; xp[3] = v.w;
    }
    __syncthreads();

    const int fg = (t & 15) * 4;
    const int r0 = (t >> 4) * 4;
    float acc[4][4] = {};

#pragma unroll
    for (int k = 0; k < 64; k++) {
        float4 wv = *(const float4*)(Ws + k * 64 + fg);
#pragma unroll
        for (int r = 0; r < 4; r++) {
            float xr = xs[(r0 + r) * 65 + k];
            acc[r][0] = fmaf(xr, wv.x, acc[r][0]);
            acc[r][1] = fmaf(xr, wv.y, acc[r][1]);
            acc[r][2] = fmaf(xr, wv.z, acc[r][2]);
            acc[r][3] = fmaf(xr, wv.w, acc[r][3]);
        }
    }

    float4 bp = b_post ? *(const float4*)(b_post + fg) : make_float4(0.f, 0.f, 0.f, 0.f);
#pragma unroll
    for (int r = 0; r < 4; r++) {
        int row = row0 + r0 + r;
        if (row >= n_rows) break;
        float sc = post_scale ? dinv[row] : 1.0f;
        float4 o;
        o.x = fmaf(acc[r][0], sc, bp.x);
        o.y = fmaf(acc[r][1], sc, bp.y);
        o.z = fmaf(acc[r][2], sc, bp.z);
        o.w = fmaf(acc[r][3], sc, bp.w);
        *(float4*)(out1 + (size_t)row * 64 + fg) = o;
    }
}

// Segmented reduction over dst-CSR: B[d] = A[d] + sum_{e in [off[d],off[d+1])} A[csr[e]]
// One 64-lane wave per node, lane = feature; 4 nodes per 256-thread block.
__global__ __launch_bounds__(WG) void aggregate(
    const float* __restrict__ A, float* __restrict__ B,
    const int* __restrict__ off, const int* __restrict__ csr, int N)
{
    int node = blockIdx.x * 4 + (threadIdx.x >> 6);
    if (node >= N) return;
    int lane = threadIdx.x & 63;

    int s0 = off[node];
    int s1 = off[node + 1];
    float acc = A[(size_t)node * 64 + lane];   // self-loop

    int e = s0;
    for (; e + 4 <= s1; e += 4) {              // 4-edge ILP
        int i0 = csr[e], i1 = csr[e + 1], i2 = csr[e + 2], i3 = csr[e + 3];
        float v0 = A[(size_t)i0 * 64 + lane];
        float v1 = A[(size_t)i1 * 64 + lane];
        float v2 = A[(size_t)i2 * 64 + lane];
        float v3 = A[(size_t)i3 * 64 + lane];
        acc += (v0 + v1) + (v2 + v3);
    }
    for (; e < s1; e++)
        acc += A[(size_t)csr[e] * 64 + lane];

    B[(size_t)node * 64 + lane] = acc;
}

extern "C" void kernel_launch(void* const* d_in, const int* in_sizes, int n_in,
                              void* d_out, int out_size, void* d_ws, size_t ws_size,
                              hipStream_t stream) {
    const float* x  = (const float*)d_in[0];
    const int*   ei = (const int*)d_in[1];
    const float* W1 = (const float*)d_in[2];
    const float* b1 = (const float*)d_in[3];
    const float* W2 = (const float*)d_in[4];
    const float* b2 = (const float*)d_in[5];
    const float* W3 = (const float*)d_in[6];
    const float* b3 = (const float*)d_in[7];
    float* out = (float*)d_out;

    const int N = in_sizes[0] / 64;    // 100000
    const int E = in_sizes[1] / 2;     // 1250000

    // workspace layout
    int*   hist = (int*)d_ws;                       // N ints (later: cursor)
    int*   off  = hist + N;                         // N+1 ints
    int*   csr  = off + (N + 1);                    // E ints
    int*   blk  = csr + E;                          // 256 ints (block sums)
    float* dinv = (float*)(blk + 256);              // N floats
    float* A    = dinv + N;                         // N*64 floats (hs)
    float* B    = A + (size_t)N * 64;               // N*64 floats (agg)

    const int gN = (N + WG - 1) / WG;
    const int gE = (E + WG - 1) / WG;
    const int gG = (N + 63) / 64;
    const int gA = (N + 3) / 4;
    const int nb = (N + 1023) / 1024;               // scan blocks (98 <= 256)

    // CSR build (per call; ws is re-poisoned every launch)
    hist_init <<<gN, WG, 0, stream>>>(hist, N);
    hist_count<<<gE, WG, 0, stream>>>(ei, hist, E);
    deg_rsqrt <<<gN, WG, 0, stream>>>(hist, dinv, N);
    scan_p1   <<<nb, WG, 0, stream>>>(hist, off, blk, N);
    scan_p2   <<<1,  WG, 0, stream>>>(blk, nb, off, N);
    scan_p3   <<<gN, WG, 0, stream>>>(off, blk, hist, N);   // hist becomes cursor
    csr_fill  <<<gE, WG, 0, stream>>>(ei, hist, csr, E);

    // Layer 1: A = dinv.*(x@W1); B = A[d] + sum A[src]
    gemm_fused<<<gG, WG, 0, stream>>>(x, W1, dinv, nullptr, 0, 1, nullptr, A, N);
    aggregate <<<gA, WG, 0, stream>>>(A, B, off, csr, N);

    // Layer 2: in = B (pre: relu(dinv*v + b1)); A = dinv.*(h@W2); B = agg
    gemm_fused<<<gG, WG, 0, stream>>>(B, W2, dinv, b1, 1, 1, nullptr, A, N);
    aggregate <<<gA, WG, 0, stream>>>(A, B, off, csr, N);

    // Layer 3: in = B (pre: relu(dinv*v + b2)); out = h@W3 + b3
    gemm_fused<<<gG, WG, 0, stream>>>(B, W3, dinv, b2, 1, 0, b3, out, N);
}

// Round 4
// 426.501 us; speedup vs baseline: 5.6261x; 1.1536x over previous
//
#include <hip/hip_runtime.h>
#include <hip/hip_bf16.h>

// GCN encoder: 3 layers on N=100000 nodes, E=1250000 edges, 64 features.
// gcn(x) = relu(D^-1/2 (A+I) D^-1/2 (xW) + b)
// Folding: hs = dinv .* (xW);  agg[d] = hs[d] + sum_{s->d} hs[s];
//          next layer's GEMM applies relu(dinv[d]*agg + b) as its pre-transform.
// R1: dst-CSR + gather segmented reduction (no fp32 atomics).
// R2: 3-phase hierarchical scan (single-block scan was 258us on 1 CU).
// R3: csr_fill had WRITE_SIZE=86MB (16x line-migration amplification from
//     scattered 4B atomic-positioned writes). Replaced with bucketed 2-phase
//     build: partition edges into 512-node dst-buckets (pairs buffer aliased
//     on B), then per-bucket block fills its private csr window via LDS cursors.

#define WG 256
#define BSHIFT 9                 // 512 nodes per bucket
#define BSIZE  (1 << BSHIFT)
#define PCHUNK 2048              // edges per partition block (8 per thread)

__global__ __launch_bounds__(WG) void hist_init(int* __restrict__ hist, int N) {
    int i = blockIdx.x * WG + threadIdx.x;
    if (i < N) hist[i] = 0;
}

__global__ __launch_bounds__(WG) void hist_count(const int* __restrict__ ei,
                                                 int* __restrict__ hist, int E) {
    int e = blockIdx.x * WG + threadIdx.x;
    if (e < E) atomicAdd(&hist[ei[E + e]], 1);   // dst row
}

__global__ __launch_bounds__(WG) void deg_rsqrt(const int* __restrict__ hist,
                                                float* __restrict__ dinv, int N) {
    int i = blockIdx.x * WG + threadIdx.x;
    if (i < N) dinv[i] = rsqrtf((float)(hist[i] + 1));   // +1 self-loop
}

// ---- 3-phase exclusive scan of hist[N] -> off[N+1] ----
__global__ __launch_bounds__(WG) void scan_p1(const int* __restrict__ hist,
                                              int* __restrict__ off,
                                              int* __restrict__ blk_sums, int N) {
    __shared__ int sums[WG];
    const int t = threadIdx.x;
    const int base = blockIdx.x * 1024 + t * 4;
    int v[4];
    int s = 0;
#pragma unroll
    for (int i = 0; i < 4; i++) {
        int idx = base + i;
        v[i] = (idx < N) ? hist[idx] : 0;
        s += v[i];
    }
    sums[t] = s;
    __syncthreads();
    for (int ofs = 1; ofs < WG; ofs <<= 1) {
        int u = (t >= ofs) ? sums[t - ofs] : 0;
        __syncthreads();
        sums[t] += u;
        __syncthreads();
    }
    int run = sums[t] - s;
#pragma unroll
    for (int i = 0; i < 4; i++) {
        int idx = base + i;
        if (idx < N) off[idx] = run;
        run += v[i];
    }
    if (t == WG - 1) blk_sums[blockIdx.x] = sums[WG - 1];
}

__global__ __launch_bounds__(WG) void scan_p2(int* __restrict__ blk_sums, int nb,
                                              int* __restrict__ off, int N) {
    __shared__ int sums[WG];
    const int t = threadIdx.x;
    int s = (t < nb) ? blk_sums[t] : 0;
    sums[t] = s;
    __syncthreads();
    for (int ofs = 1; ofs < WG; ofs <<= 1) {
        int u = (t >= ofs) ? sums[t - ofs] : 0;
        __syncthreads();
        sums[t] += u;
        __syncthreads();
    }
    if (t < nb) blk_sums[t] = sums[t] - s;
    if (t == WG - 1) off[N] = sums[WG - 1];
}

__global__ __launch_bounds__(WG) void scan_p3(int* __restrict__ off,
                                              const int* __restrict__ blk_sums, int N) {
    int i = blockIdx.x * WG + threadIdx.x;
    if (i < N) off[i] += blk_sums[i >> 10];
}

// Bucket cursor init: cur2[b] = off[b*512]  (start of bucket b's csr window)
__global__ __launch_bounds__(WG) void bcur_init(const int* __restrict__ off,
                                                int* __restrict__ cur2, int nbk) {
    int b = blockIdx.x * WG + threadIdx.x;
    if (b < nbk) cur2[b] = off[b << BSHIFT];
}

// Partition edges by dst-bucket into packed pairs ((dst&511)<<32 | src).
// Per block: LDS histogram of its 2048 edges -> one global atomic per touched
// bucket reserves a contiguous run -> writes land in <=2-writer cache lines.
__global__ __launch_bounds__(WG) void partition(const int* __restrict__ ei,
                                                int* __restrict__ cur2,
                                                unsigned long long* __restrict__ pairs,
                                                int E) {
    __shared__ int hist[256];
    __shared__ int gbase[256];
    const int t = threadIdx.x;
    const int base = blockIdx.x * PCHUNK;

    hist[t] = 0;
    __syncthreads();

    int s[8], d[8], r[8];
#pragma unroll
    for (int i = 0; i < 8; i++) {
        int e = base + i * WG + t;           // coalesced
        bool ok = e < E;
        s[i] = ok ? ei[e] : 0;
        d[i] = ok ? ei[E + e] : 0;
        r[i] = ok ? atomicAdd(&hist[d[i] >> BSHIFT], 1) : 0;
        if (!ok) d[i] = -1;
    }
    __syncthreads();

    if (hist[t] > 0) gbase[t] = atomicAdd(&cur2[t], hist[t]);
    __syncthreads();

#pragma unroll
    for (int i = 0; i < 8; i++) {
        if (d[i] >= 0) {
            int b = d[i] >> BSHIFT;
            unsigned long long p =
                ((unsigned long long)(unsigned)(d[i] & (BSIZE - 1)) << 32) |
                (unsigned)s[i];
            pairs[gbase[b] + r[i]] = p;
        }
    }
}

// Per-bucket csr fill: one block owns bucket b's private csr window; LDS
// cursors over its 512 nodes. All csr writes from exactly one block.
__global__ __launch_bounds__(WG) void csr_local(const unsigned long long* __restrict__ pairs,
                                                const int* __restrict__ off,
                                                int* __restrict__ csr, int N) {
    __shared__ int cur[BSIZE];
    const int b = blockIdx.x;
    const int node0 = b << BSHIFT;
    const int nlocal = min(BSIZE, N - node0);
    const int t = threadIdx.x;

    for (int i = t; i < nlocal; i += WG) cur[i] = off[node0 + i];
    __syncthreads();

    const int start = off[node0];
    const int end = off[min(node0 + BSIZE, N)];
    for (int e = start + t; e < end; e += WG) {
        unsigned long long p = pairs[e];
        int local = (int)(p >> 32);
        int src = (int)(p & 0xffffffffu);
        int pos = atomicAdd(&cur[local], 1);
        csr[pos] = src;
    }
}

// Fused GEMM: out = post( pre(in) @ W )
//   pre(v)  = pre_flag ? relu(dinv[row]*v + b_pre[col]) : v
//   post(a) = (post_scale ? dinv[row]*a : a) + (b_post ? b_post[col] : 0)
__global__ __launch_bounds__(WG) void gemm_fused(
    const float* __restrict__ in, const float* __restrict__ W,
    const float* __restrict__ dinv, const float* __restrict__ b_pre, int pre_flag,
    int post_scale, const float* __restrict__ b_post,
    float* __restrict__ out1, int n_rows)
{
    __shared__ float Ws[64 * 64];
    __shared__ float xs[64 * 65];

    const int t = threadIdx.x;
    const int row0 = blockIdx.x * 64;

    const float4* W4 = (const float4*)W;
    float4* Ws4 = (float4*)Ws;
#pragma unroll
    for (int i = 0; i < 4; i++) Ws4[i * WG + t] = W4[i * WG + t];

#pragma unroll
    for (int i = 0; i < 4; i++) {
        int j = i * WG + t;
        int rr = j >> 4;
        int c  = (j & 15) * 4;
        int row = row0 + rr;
        float4 v = make_float4(0.f, 0.f, 0.f, 0.f);
        if (row < n_rows) {
            v = *(const float4*)(in + (size_t)row * 64 + c);
            if (pre_flag) {
                float dv = dinv[row];
                float4 bb = *(const float4*)(b_pre + c);
                v.x = fmaxf(fmaf(dv, v.x, bb.x), 0.f);
                v.y = fmaxf(fmaf(dv, v.y, bb.y), 0.f);
                v.z = fmaxf(fmaf(dv, v.z, bb.z), 0.f);
                v.w = fmaxf(fmaf(dv, v.w, bb.w), 0.f);
            }
        }
        float* xp = xs + rr * 65 + c;
        xp[0] = v.x; xp[1] = v.y; xp[2] = v.z; xp[3] = v.w;
    }
    __syncthreads();

    const int fg = (t & 15) * 4;
    const int r0 = (t >> 4) * 4;
    float acc[4][4] = {};

#pragma unroll
    for (int k = 0; k < 64; k++) {
        float4 wv = *(const float4*)(Ws + k * 64 + fg);
#pragma unroll
        for (int r = 0; r < 4; r++) {
            float xr = xs[(r0 + r) * 65 + k];
            acc[r][0] = fmaf(xr, wv.x, acc[r][0]);
            acc[r][1] = fmaf(xr, wv.y, acc[r][1]);
            acc[r][2] = fmaf(xr, wv.z, acc[r][2]);
            acc[r][3] = fmaf(xr, wv.w, acc[r][3]);
        }
    }

    float4 bp = b_post ? *(const float4*)(b_post + fg) : make_float4(0.f, 0.f, 0.f, 0.f);
#pragma unroll
    for (int r = 0; r < 4; r++) {
        int row = row0 + r0 + r;
        if (row >= n_rows) break;
        float sc = post_scale ? dinv[row] : 1.0f;
        float4 o;
        o.x = fmaf(acc[r][0], sc, bp.x);
        o.y = fmaf(acc[r][1], sc, bp.y);
        o.z = fmaf(acc[r][2], sc, bp.z);
        o.w = fmaf(acc[r][3], sc, bp.w);
        *(float4*)(out1 + (size_t)row * 64 + fg) = o;
    }
}

// Segmented reduction over dst-CSR: B[d] = A[d] + sum A[csr[e]]
// One 64-lane wave per node, lane = feature; 4 nodes per block.
__global__ __launch_bounds__(WG) void aggregate(
    const float* __restrict__ A, float* __restrict__ B,
    const int* __restrict__ off, const int* __restrict__ csr, int N)
{
    int node = blockIdx.x * 4 + (threadIdx.x >> 6);
    if (node >= N) return;
    int lane = threadIdx.x & 63;

    int s0 = off[node];
    int s1 = off[node + 1];
    float acc = A[(size_t)node * 64 + lane];   // self-loop

    int e = s0;
    for (; e + 4 <= s1; e += 4) {
        int i0 = csr[e], i1 = csr[e + 1], i2 = csr[e + 2], i3 = csr[e + 3];
        float v0 = A[(size_t)i0 * 64 + lane];
        float v1 = A[(size_t)i1 * 64 + lane];
        float v2 = A[(size_t)i2 * 64 + lane];
        float v3 = A[(size_t)i3 * 64 + lane];
        acc += (v0 + v1) + (v2 + v3);
    }
    for (; e < s1; e++)
        acc += A[(size_t)csr[e] * 64 + lane];

    B[(size_t)node * 64 + lane] = acc;
}

extern "C" void kernel_launch(void* const* d_in, const int* in_sizes, int n_in,
                              void* d_out, int out_size, void* d_ws, size_t ws_size,
                              hipStream_t stream) {
    const float* x  = (const float*)d_in[0];
    const int*   ei = (const int*)d_in[1];
    const float* W1 = (const float*)d_in[2];
    const float* b1 = (const float*)d_in[3];
    const float* W2 = (const float*)d_in[4];
    const float* b2 = (const float*)d_in[5];
    const float* W3 = (const float*)d_in[6];
    const float* b3 = (const float*)d_in[7];
    float* out = (float*)d_out;

    const int N = in_sizes[0] / 64;    // 100000
    const int E = in_sizes[1] / 2;     // 1250000

    // workspace layout
    int*   hist = (int*)d_ws;                       // N
    int*   off  = hist + N;                         // N+1
    int*   csr  = off + (N + 1);                    // E
    int*   blk  = csr + E;                          // 256 (scan block sums)
    int*   cur2 = blk + 256;                        // 256 (bucket cursors)
    uintptr_t pa = (uintptr_t)(cur2 + 256);
    pa = (pa + 255) & ~(uintptr_t)255;
    float* dinv = (float*)pa;                       // N
    float* A    = dinv + N;                         // N*64 (hs)
    float* B    = A + (size_t)N * 64;               // N*64 (agg)
    unsigned long long* pairs = (unsigned long long*)B;  // aliased: dead until aggregate

    const int gN  = (N + WG - 1) / WG;
    const int gE  = (E + WG - 1) / WG;
    const int gG  = (N + 63) / 64;
    const int gA  = (N + 3) / 4;
    const int nb  = (N + 1023) / 1024;              // scan blocks (98)
    const int nbk = (N + BSIZE - 1) / BSIZE;        // buckets (196)
    const int gP  = (E + PCHUNK - 1) / PCHUNK;      // partition blocks (611)

    // CSR build (per call; ws is re-poisoned every launch)
    hist_init <<<gN, WG, 0, stream>>>(hist, N);
    hist_count<<<gE, WG, 0, stream>>>(ei, hist, E);
    deg_rsqrt <<<gN, WG, 0, stream>>>(hist, dinv, N);
    scan_p1   <<<nb, WG, 0, stream>>>(hist, off, blk, N);
    scan_p2   <<<1,  WG, 0, stream>>>(blk, nb, off, N);
    scan_p3   <<<gN, WG, 0, stream>>>(off, blk, N);
    bcur_init <<<1,  WG, 0, stream>>>(off, cur2, nbk);
    partition <<<gP, WG, 0, stream>>>(ei, cur2, pairs, E);
    csr_local <<<nbk, WG, 0, stream>>>(pairs, off, csr, N);

    // Layer 1: A = dinv.*(x@W1); B = A[d] + sum A[src]
    gemm_fused<<<gG, WG, 0, stream>>>(x, W1, dinv, nullptr, 0, 1, nullptr, A, N);
    aggregate <<<gA, WG, 0, stream>>>(A, B, off, csr, N);

    // Layer 2: in = B (pre: relu(dinv*v + b1)); A = dinv.*(h@W2); B = agg
    gemm_fused<<<gG, WG, 0, stream>>>(B, W2, dinv, b1, 1, 1, nullptr, A, N);
    aggregate <<<gA, WG, 0, stream>>>(A, B, off, csr, N);

    // Layer 3: in = B (pre: relu(dinv*v + b2)); out = h@W3 + b3
    gemm_fused<<<gG, WG, 0, stream>>>(B, W3, dinv, b2, 1, 0, b3, out, N);
}

// Round 5
// 364.816 us; speedup vs baseline: 6.5774x; 1.1691x over previous
//
#include <hip/hip_runtime.h>
#include <hip/hip_bf16.h>

// GCN encoder: 3 layers on N=100000 nodes, E=1250000 edges, 64 features.
// gcn(x) = relu(D^-1/2 (A+I) D^-1/2 (xW) + b)
// Folding: hs = dinv .* (xW);  agg[d] = hs[d] + sum_{s->d} hs[s];
//          next layer's GEMM applies relu(dinv[d]*agg + b) as its pre-transform.
// R1: dst-CSR + gather segmented reduction (no fp32 atomics).
// R2: 3-phase hierarchical scan (single-block scan was 258us on 1 CU).
// R3: bucketed 2-phase CSR build (csr_fill had 16x write amplification).
// R4: (a) hs stored bf16 -> gather volume halved (fp32 accumulate);
//     (b) histogram-free build: fixed-capacity bucket slabs + per-bucket LDS
//         hist/scan/dinv (kills hist_count's 1.25M scattered atomics + scans);
//     (c) gemm xs stride 65->68 so k-loop x reads are ds_read_b128.

#define WG 256
#define BSHIFT 9                 // 512 nodes per bucket
#define BSIZE  (1 << BSHIFT)
#define BCAP   8192              // pair slots per bucket (mean 6400, sd ~80)
#define PCHUNK 2048              // edges per partition block (8 per thread)
#define XS_LD  68                // xs leading dim: 16B-aligned rows, 2-way b128 reads

// cur2[b] = b*BCAP  (write cursor into bucket slab)
__global__ __launch_bounds__(WG) void bcur_init(int* __restrict__ cur2, int nbk) {
    int b = threadIdx.x;
    if (b < nbk) cur2[b] = b * BCAP;
}

// Partition edges by dst-bucket into packed pairs ((dst&511)<<32 | src) in
// fixed per-bucket slabs. Per block: LDS histogram -> one global atomic per
// touched bucket reserves a contiguous run.
__global__ __launch_bounds__(WG) void partition(const int* __restrict__ ei,
                                                int* __restrict__ cur2,
                                                unsigned long long* __restrict__ pairs,
                                                int E) {
    __shared__ int hist[256];
    __shared__ int gbase[256];
    const int t = threadIdx.x;
    const int base = blockIdx.x * PCHUNK;

    hist[t] = 0;
    __syncthreads();

    int s[8], d[8], r[8];
#pragma unroll
    for (int i = 0; i < 8; i++) {
        int e = base + i * WG + t;           // coalesced
        bool ok = e < E;
        s[i] = ok ? ei[e] : 0;
        d[i] = ok ? ei[E + e] : 0;
        r[i] = ok ? atomicAdd(&hist[d[i] >> BSHIFT], 1) : 0;
        if (!ok) d[i] = -1;
    }
    __syncthreads();

    if (hist[t] > 0) gbase[t] = atomicAdd(&cur2[t], hist[t]);
    __syncthreads();

#pragma unroll
    for (int i = 0; i < 8; i++) {
        if (d[i] >= 0) {
            int b = d[i] >> BSHIFT;
            unsigned long long p =
                ((unsigned long long)(unsigned)(d[i] & (BSIZE - 1)) << 32) |
                (unsigned)s[i];
            pairs[gbase[b] + r[i]] = p;
        }
    }
}

// Scan bucket totals (cur2[b]-b*BCAP) -> bbase[b] (exclusive); off[N] = E.
__global__ __launch_bounds__(WG) void bsum_scan(const int* __restrict__ cur2,
                                                int* __restrict__ bbase, int nbk,
                                                int* __restrict__ off, int N) {
    __shared__ int sums[WG];
    const int t = threadIdx.x;
    int s = (t < nbk) ? (cur2[t] - t * BCAP) : 0;
    sums[t] = s;
    __syncthreads();
    for (int ofs = 1; ofs < WG; ofs <<= 1) {
        int u = (t >= ofs) ? sums[t - ofs] : 0;
        __syncthreads();
        sums[t] += u;
        __syncthreads();
    }
    if (t < nbk) bbase[t] = sums[t] - s;
    if (t == WG - 1) off[N] = sums[WG - 1];
}

// Per-bucket: LDS histogram over 512 local nodes -> LDS scan -> off/dinv/cursors
// -> fill private csr window. All csr writes from exactly one block.
__global__ __launch_bounds__(WG) void csr_local(const unsigned long long* __restrict__ pairs,
                                                const int* __restrict__ cur2,
                                                const int* __restrict__ bbase,
                                                int* __restrict__ off,
                                                float* __restrict__ dinv,
                                                int* __restrict__ csr, int N) {
    __shared__ int h[BSIZE];
    __shared__ int cur[BSIZE];
    __shared__ int sums[WG];
    const int b = blockIdx.x;
    const int t = threadIdx.x;
    const int node0 = b << BSHIFT;
    const int nlocal = min(BSIZE, N - node0);
    const int pstart = b * BCAP;
    const int pend = cur2[b];
    const int base = bbase[b];

    h[t] = 0; h[t + WG] = 0;
    __syncthreads();

    for (int e = pstart + t; e < pend; e += WG)
        atomicAdd(&h[(int)(pairs[e] >> 32)], 1);
    __syncthreads();

    // scan 512 (2 per thread)
    int a0 = h[2 * t], a1 = h[2 * t + 1];
    int s = a0 + a1;
    sums[t] = s;
    __syncthreads();
    for (int ofs = 1; ofs < WG; ofs <<= 1) {
        int u = (t >= ofs) ? sums[t - ofs] : 0;
        __syncthreads();
        sums[t] += u;
        __syncthreads();
    }
    int run = base + sums[t] - s;
    if (2 * t < nlocal) {
        off[node0 + 2 * t] = run;
        cur[2 * t] = run;
        dinv[node0 + 2 * t] = rsqrtf((float)(a0 + 1));
    }
    if (2 * t + 1 < nlocal) {
        off[node0 + 2 * t + 1] = run + a0;
        cur[2 * t + 1] = run + a0;
        dinv[node0 + 2 * t + 1] = rsqrtf((float)(a1 + 1));
    }
    __syncthreads();

    for (int e = pstart + t; e < pend; e += WG) {
        unsigned long long p = pairs[e];
        int local = (int)(p >> 32);
        int src = (int)(p & 0xffffffffu);
        int pos = atomicAdd(&cur[local], 1);
        csr[pos] = src;
    }
}

// Fused GEMM: out = post( pre(in) @ W )
//   pre(v)  = pre_flag ? relu(dinv[row]*v + b_pre[col]) : v
//   post(a) = (post_scale ? dinv[row]*a : a) + (b_post ? b_post[col] : 0)
// out_bf16: store as bf16 (hs buffer A), else fp32.
__global__ __launch_bounds__(WG) void gemm_fused(
    const float* __restrict__ in, const float* __restrict__ W,
    const float* __restrict__ dinv, const float* __restrict__ b_pre, int pre_flag,
    int post_scale, const float* __restrict__ b_post,
    void* __restrict__ out1, int out_bf16, int n_rows)
{
    __shared__ float Ws[64 * 64];
    __shared__ float xs[64 * XS_LD];

    const int t = threadIdx.x;
    const int row0 = blockIdx.x * 64;

    const float4* W4 = (const float4*)W;
    float4* Ws4 = (float4*)Ws;
#pragma unroll
    for (int i = 0; i < 4; i++) Ws4[i * WG + t] = W4[i * WG + t];

#pragma unroll
    for (int i = 0; i < 4; i++) {
        int j = i * WG + t;
        int rr = j >> 4;
        int c  = (j & 15) * 4;
        int row = row0 + rr;
        float4 v = make_float4(0.f, 0.f, 0.f, 0.f);
        if (row < n_rows) {
            v = *(const float4*)(in + (size_t)row * 64 + c);
            if (pre_flag) {
                float dv = dinv[row];
                float4 bb = *(const float4*)(b_pre + c);
                v.x = fmaxf(fmaf(dv, v.x, bb.x), 0.f);
                v.y = fmaxf(fmaf(dv, v.y, bb.y), 0.f);
                v.z = fmaxf(fmaf(dv, v.z, bb.z), 0.f);
                v.w = fmaxf(fmaf(dv, v.w, bb.w), 0.f);
            }
        }
        float* xp = xs + rr * XS_LD + c;
        xp[0] = v.x; xp[1] = v.y; xp[2] = v.z; xp[3] = v.w;
    }
    __syncthreads();

    const int fg = (t & 15) * 4;
    const int r0 = (t >> 4) * 4;
    float acc[4][4] = {};

#pragma unroll
    for (int kq = 0; kq < 64; kq += 4) {          // k-quads: b128 xs reads
        float4 xr[4];
#pragma unroll
        for (int r = 0; r < 4; r++)
            xr[r] = *(const float4*)(xs + (r0 + r) * XS_LD + kq);
#pragma unroll
        for (int kk = 0; kk < 4; kk++) {
            float4 wv = *(const float4*)(Ws + (kq + kk) * 64 + fg);
#pragma unroll
            for (int r = 0; r < 4; r++) {
                float xv = ((const float*)&xr[r])[kk];
                acc[r][0] = fmaf(xv, wv.x, acc[r][0]);
                acc[r][1] = fmaf(xv, wv.y, acc[r][1]);
                acc[r][2] = fmaf(xv, wv.z, acc[r][2]);
                acc[r][3] = fmaf(xv, wv.w, acc[r][3]);
            }
        }
    }

    float4 bp = b_post ? *(const float4*)(b_post + fg) : make_float4(0.f, 0.f, 0.f, 0.f);
#pragma unroll
    for (int r = 0; r < 4; r++) {
        int row = row0 + r0 + r;
        if (row >= n_rows) break;
        float sc = post_scale ? dinv[row] : 1.0f;
        float4 o;
        o.x = fmaf(acc[r][0], sc, bp.x);
        o.y = fmaf(acc[r][1], sc, bp.y);
        o.z = fmaf(acc[r][2], sc, bp.z);
        o.w = fmaf(acc[r][3], sc, bp.w);
        if (out_bf16) {
            union { __hip_bfloat16 h[4]; ushort4 u; } pk;
            pk.h[0] = __float2bfloat16(o.x);
            pk.h[1] = __float2bfloat16(o.y);
            pk.h[2] = __float2bfloat16(o.z);
            pk.h[3] = __float2bfloat16(o.w);
            *(ushort4*)((unsigned short*)out1 + ((size_t)row << 6) + fg) = pk.u;
        } else {
            *(float4*)((float*)out1 + ((size_t)row << 6) + fg) = o;
        }
    }
}

// Segmented reduction over dst-CSR: B[d] = A[d] + sum A[csr[e]]  (A is bf16)
// One 64-lane wave per node, lane = feature; 4 nodes per block.
__global__ __launch_bounds__(WG) void aggregate(
    const __hip_bfloat16* __restrict__ A, float* __restrict__ B,
    const int* __restrict__ off, const int* __restrict__ csr, int N)
{
    int node = blockIdx.x * 4 + (threadIdx.x >> 6);
    if (node >= N) return;
    int lane = threadIdx.x & 63;

    int s0 = off[node];
    int s1 = off[node + 1];
    float acc = __bfloat162float(A[((size_t)node << 6) + lane]);   // self-loop

    int e = s0;
    for (; e + 4 <= s1; e += 4) {              // 4-edge ILP
        int i0 = csr[e], i1 = csr[e + 1], i2 = csr[e + 2], i3 = csr[e + 3];
        float v0 = __bfloat162float(A[((size_t)i0 << 6) + lane]);
        float v1 = __bfloat162float(A[((size_t)i1 << 6) + lane]);
        float v2 = __bfloat162float(A[((size_t)i2 << 6) + lane]);
        float v3 = __bfloat162float(A[((size_t)i3 << 6) + lane]);
        acc += (v0 + v1) + (v2 + v3);
    }
    for (; e < s1; e++)
        acc += __bfloat162float(A[((size_t)csr[e] << 6) + lane]);

    B[((size_t)node << 6) + lane] = acc;
}

extern "C" void kernel_launch(void* const* d_in, const int* in_sizes, int n_in,
                              void* d_out, int out_size, void* d_ws, size_t ws_size,
                              hipStream_t stream) {
    const float* x  = (const float*)d_in[0];
    const int*   ei = (const int*)d_in[1];
    const float* W1 = (const float*)d_in[2];
    const float* b1 = (const float*)d_in[3];
    const float* W2 = (const float*)d_in[4];
    const float* b2 = (const float*)d_in[5];
    const float* W3 = (const float*)d_in[6];
    const float* b3 = (const float*)d_in[7];
    float* out = (float*)d_out;

    const int N = in_sizes[0] / 64;    // 100000
    const int E = in_sizes[1] / 2;     // 1250000
    const int nbk = (N + BSIZE - 1) / BSIZE;        // 196 buckets

    // workspace layout
    int*   off  = (int*)d_ws;                       // N+1
    int*   csr  = off + (N + 1);                    // E
    int*   cur2 = csr + E;                          // 256
    int*   bbase= cur2 + 256;                       // 256
    uintptr_t pa = (uintptr_t)(bbase + 256);
    pa = (pa + 255) & ~(uintptr_t)255;
    float* dinv = (float*)pa;                       // N
    __hip_bfloat16* A = (__hip_bfloat16*)(dinv + N);// N*64 bf16 (hs)
    float* B    = (float*)(A + (size_t)N * 64);     // N*64 fp32 (agg)
    unsigned long long* pairs = (unsigned long long*)B;  // aliased: dead until agg1
                                                    // needs nbk*BCAP*8 = 12.9MB <= 25.6MB

    const int gG = (N + 63) / 64;
    const int gA = (N + 3) / 4;
    const int gP = (E + PCHUNK - 1) / PCHUNK;

    // CSR build (per call; ws re-poisoned every launch)
    bcur_init<<<1,   WG, 0, stream>>>(cur2, nbk);
    partition<<<gP,  WG, 0, stream>>>(ei, cur2, pairs, E);
    bsum_scan<<<1,   WG, 0, stream>>>(cur2, bbase, nbk, off, N);
    csr_local<<<nbk, WG, 0, stream>>>(pairs, cur2, bbase, off, dinv, csr, N);

    // Layer 1: A = bf16(dinv.*(x@W1)); B = A[d] + sum A[src]
    gemm_fused<<<gG, WG, 0, stream>>>(x, W1, dinv, nullptr, 0, 1, nullptr, A, 1, N);
    aggregate <<<gA, WG, 0, stream>>>(A, B, off, csr, N);

    // Layer 2: in = B (pre: relu(dinv*v + b1)); A = bf16(dinv.*(h@W2)); B = agg
    gemm_fused<<<gG, WG, 0, stream>>>(B, W2, dinv, b1, 1, 1, nullptr, A, 1, N);
    aggregate <<<gA, WG, 0, stream>>>(A, B, off, csr, N);

    // Layer 3: in = B (pre: relu(dinv*v + b2)); out = h@W3 + b3 (fp32)
    gemm_fused<<<gG, WG, 0, stream>>>(B, W3, dinv, b2, 1, 0, b3, out, 0, N);
}

// Round 6
// 358.314 us; speedup vs baseline: 6.6968x; 1.0181x over previous
//
#include <hip/hip_runtime.h>
#include <hip/hip_bf16.h>

// GCN encoder: 3 layers on N=100000 nodes, E=1250000 edges, 64 features.
// gcn(x) = relu(D^-1/2 (A+I) D^-1/2 (xW) + b)
// Folding: hs = dinv .* (xW);  agg[d] = hs[d] + sum_{s->d} hs[s];
//          next layer's GEMM applies relu(dinv[d]*agg + b) as its pre-transform.
// R1: dst-CSR + gather segmented reduction (no fp32 atomics).
// R2: hierarchical scan.  R3: bucketed 2-phase CSR build.
// R4: bf16 hs, histogram-free slab build, b128 gemm k-loop.
// R5: aggregate was latency-bound (VALU 32%, HBM 23%): half-wave uint(bf16x2)
//     gathers, 8 edges in flight/wave, shfl-broadcast prefetched indices.
//     partition: LDS-staged bucket-ordered output (coalesced store runs).
//     csr_local: 1024 threads (was 196 blocks x 256 = latency-serial).

#define WG 256
#define BSHIFT 9                 // 512 nodes per bucket
#define BSIZE  (1 << BSHIFT)
#define BCAP   8192              // pair slots per bucket (mean 6400, sd ~80)
#define PCHUNK 2048              // edges per partition block (8 per thread)
#define XS_LD  68                // xs leading dim: 16B-aligned rows, b128 reads

// cur2[b] = b*BCAP  (write cursor into bucket slab)
__global__ __launch_bounds__(WG) void bcur_init(int* __restrict__ cur2, int nbk) {
    int b = threadIdx.x;
    if (b < nbk) cur2[b] = b * BCAP;
}

// Partition edges by dst-bucket into packed pairs ((dst&511)<<32 | src) in
// fixed per-bucket slabs. LDS histogram -> one global atomic per touched
// bucket -> stage (pair,dest) in LDS in bucket-slot order -> linear output
// loop: consecutive threads write consecutive dests within a bucket run.
__global__ __launch_bounds__(WG) void partition(const int* __restrict__ ei,
                                                int* __restrict__ cur2,
                                                unsigned long long* __restrict__ pairs,
                                                int E) {
    __shared__ int hist[256];
    __shared__ int gbase[256];
    __shared__ int lb[256];
    __shared__ int sums[WG];
    __shared__ unsigned long long sp[PCHUNK];
    __shared__ int sd[PCHUNK];
    const int t = threadIdx.x;
    const int base = blockIdx.x * PCHUNK;
    const int total = min(PCHUNK, E - base);

    hist[t] = 0;
    __syncthreads();

    int s[8], d[8], r[8];
#pragma unroll
    for (int i = 0; i < 8; i++) {
        int e = base + i * WG + t;           // coalesced
        bool ok = e < E;
        s[i] = ok ? ei[e] : 0;
        d[i] = ok ? ei[E + e] : 0;
        r[i] = ok ? atomicAdd(&hist[d[i] >> BSHIFT], 1) : 0;
        if (!ok) d[i] = -1;
    }
    __syncthreads();

    int hv = hist[t];
    if (hv > 0) gbase[t] = atomicAdd(&cur2[t], hv);
    // exclusive scan of hist -> lb (local slot base per bucket)
    sums[t] = hv;
    __syncthreads();
    for (int ofs = 1; ofs < WG; ofs <<= 1) {
        int u = (t >= ofs) ? sums[t - ofs] : 0;
        __syncthreads();
        sums[t] += u;
        __syncthreads();
    }
    lb[t] = sums[t] - hv;
    __syncthreads();

#pragma unroll
    for (int i = 0; i < 8; i++) {
        if (d[i] >= 0) {
            int b = d[i] >> BSHIFT;
            int slot = lb[b] + r[i];
            sp[slot] = ((unsigned long long)(unsigned)(d[i] & (BSIZE - 1)) << 32) |
                       (unsigned)s[i];
            sd[slot] = gbase[b] + r[i];
        }
    }
    __syncthreads();

    for (int j = t; j < total; j += WG)
        pairs[sd[j]] = sp[j];
}

// Scan bucket totals (cur2[b]-b*BCAP) -> bbase[b] (exclusive); off[N] = E.
__global__ __launch_bounds__(WG) void bsum_scan(const int* __restrict__ cur2,
                                                int* __restrict__ bbase, int nbk,
                                                int* __restrict__ off, int N) {
    __shared__ int sums[WG];
    const int t = threadIdx.x;
    int s = (t < nbk) ? (cur2[t] - t * BCAP) : 0;
    sums[t] = s;
    __syncthreads();
    for (int ofs = 1; ofs < WG; ofs <<= 1) {
        int u = (t >= ofs) ? sums[t - ofs] : 0;
        __syncthreads();
        sums[t] += u;
        __syncthreads();
    }
    if (t < nbk) bbase[t] = sums[t] - s;
    if (t == WG - 1) off[N] = sums[WG - 1];
}

// Per-bucket: LDS histogram over 512 local nodes -> LDS scan -> off/dinv/cursors
// -> fill private csr window. 1024 threads (only 196 blocks exist).
__global__ __launch_bounds__(1024) void csr_local(const unsigned long long* __restrict__ pairs,
                                                  const int* __restrict__ cur2,
                                                  const int* __restrict__ bbase,
                                                  int* __restrict__ off,
                                                  float* __restrict__ dinv,
                                                  int* __restrict__ csr, int N) {
    __shared__ int h[BSIZE];
    __shared__ int cur[BSIZE];
    __shared__ int sums[1024];
    const int b = blockIdx.x;
    const int t = threadIdx.x;
    const int node0 = b << BSHIFT;
    const int nlocal = min(BSIZE, N - node0);
    const int pstart = b * BCAP;
    const int pend = cur2[b];
    const int base = bbase[b];

    if (t < BSIZE) h[t] = 0;
    __syncthreads();

    for (int e = pstart + t; e < pend; e += 1024)
        atomicAdd(&h[(int)(pairs[e] >> 32)], 1);
    __syncthreads();

    // inclusive scan over 1024 slots (only first BSIZE carry data)
    int s = (t < BSIZE) ? h[t] : 0;
    sums[t] = s;
    __syncthreads();
    for (int ofs = 1; ofs < 1024; ofs <<= 1) {
        int u = (t >= ofs) ? sums[t - ofs] : 0;
        __syncthreads();
        sums[t] += u;
        __syncthreads();
    }
    if (t < nlocal) {
        int run = base + sums[t] - s;
        off[node0 + t] = run;
        cur[t] = run;
        dinv[node0 + t] = rsqrtf((float)(s + 1));
    }
    __syncthreads();

    for (int e = pstart + t; e < pend; e += 1024) {
        unsigned long long p = pairs[e];
        int local = (int)(p >> 32);
        int src = (int)(p & 0xffffffffu);
        int pos = atomicAdd(&cur[local], 1);
        csr[pos] = src;
    }
}

// Fused GEMM: out = post( pre(in) @ W )
//   pre(v)  = pre_flag ? relu(dinv[row]*v + b_pre[col]) : v
//   post(a) = (post_scale ? dinv[row]*a : a) + (b_post ? b_post[col] : 0)
__global__ __launch_bounds__(WG) void gemm_fused(
    const float* __restrict__ in, const float* __restrict__ W,
    const float* __restrict__ dinv, const float* __restrict__ b_pre, int pre_flag,
    int post_scale, const float* __restrict__ b_post,
    void* __restrict__ out1, int out_bf16, int n_rows)
{
    __shared__ float Ws[64 * 64];
    __shared__ float xs[64 * XS_LD];

    const int t = threadIdx.x;
    const int row0 = blockIdx.x * 64;

    const float4* W4 = (const float4*)W;
    float4* Ws4 = (float4*)Ws;
#pragma unroll
    for (int i = 0; i < 4; i++) Ws4[i * WG + t] = W4[i * WG + t];

#pragma unroll
    for (int i = 0; i < 4; i++) {
        int j = i * WG + t;
        int rr = j >> 4;
        int c  = (j & 15) * 4;
        int row = row0 + rr;
        float4 v = make_float4(0.f, 0.f, 0.f, 0.f);
        if (row < n_rows) {
            v = *(const float4*)(in + (size_t)row * 64 + c);
            if (pre_flag) {
                float dv = dinv[row];
                float4 bb = *(const float4*)(b_pre + c);
                v.x = fmaxf(fmaf(dv, v.x, bb.x), 0.f);
                v.y = fmaxf(fmaf(dv, v.y, bb.y), 0.f);
                v.z = fmaxf(fmaf(dv, v.z, bb.z), 0.f);
                v.w = fmaxf(fmaf(dv, v.w, bb.w), 0.f);
            }
        }
        float* xp = xs + rr * XS_LD + c;
        xp[0] = v.x; xp[1] = v.y; xp[2] = v.z; xp[3] = v.w;
    }
    __syncthreads();

    const int fg = (t & 15) * 4;
    const int r0 = (t >> 4) * 4;
    float acc[4][4] = {};

#pragma unroll
    for (int kq = 0; kq < 64; kq += 4) {          // k-quads: b128 xs reads
        float4 xr[4];
#pragma unroll
        for (int r = 0; r < 4; r++)
            xr[r] = *(const float4*)(xs + (r0 + r) * XS_LD + kq);
#pragma unroll
        for (int kk = 0; kk < 4; kk++) {
            float4 wv = *(const float4*)(Ws + (kq + kk) * 64 + fg);
#pragma unroll
            for (int r = 0; r < 4; r++) {
                float xv = ((const float*)&xr[r])[kk];
                acc[r][0] = fmaf(xv, wv.x, acc[r][0]);
                acc[r][1] = fmaf(xv, wv.y, acc[r][1]);
                acc[r][2] = fmaf(xv, wv.z, acc[r][2]);
                acc[r][3] = fmaf(xv, wv.w, acc[r][3]);
            }
        }
    }

    float4 bp = b_post ? *(const float4*)(b_post + fg) : make_float4(0.f, 0.f, 0.f, 0.f);
#pragma unroll
    for (int r = 0; r < 4; r++) {
        int row = row0 + r0 + r;
        if (row >= n_rows) break;
        float sc = post_scale ? dinv[row] : 1.0f;
        float4 o;
        o.x = fmaf(acc[r][0], sc, bp.x);
        o.y = fmaf(acc[r][1], sc, bp.y);
        o.z = fmaf(acc[r][2], sc, bp.z);
        o.w = fmaf(acc[r][3], sc, bp.w);
        if (out_bf16) {
            union { __hip_bfloat16 h[4]; ushort4 u; } pk;
            pk.h[0] = __float2bfloat16(o.x);
            pk.h[1] = __float2bfloat16(o.y);
            pk.h[2] = __float2bfloat16(o.z);
            pk.h[3] = __float2bfloat16(o.w);
            *(ushort4*)((unsigned short*)out1 + ((size_t)row << 6) + fg) = pk.u;
        } else {
            *(float4*)((float*)out1 + ((size_t)row << 6) + fg) = o;
        }
    }
}

__device__ __forceinline__ float2 bf16x2_to_f2(unsigned u) {
    union { unsigned v; float f; } lo, hi;
    lo.v = u << 16;
    hi.v = u & 0xffff0000u;
    return make_float2(lo.f, hi.f);
}

// Segmented reduction over dst-CSR: B[d] = A[d] + sum A[csr[e]]  (A is bf16).
// One wave per node. Lane l reads uint (bf16x2) at col-pair (l&31); half-wave
// (l>>5) processes different edges; 4 edges per half-wave in flight (8/wave).
// Indices prefetched 64-at-a-time (coalesced) and broadcast via shfl.
__global__ __launch_bounds__(WG) void aggregate(
    const unsigned* __restrict__ A2, float* __restrict__ B,
    const int* __restrict__ off, const int* __restrict__ csr, int N)
{
    int node = blockIdx.x * 4 + (threadIdx.x >> 6);
    if (node >= N) return;
    const int l = threadIdx.x & 63;
    const int c = l & 31;           // col pair
    const int h = l >> 5;           // half-wave

    const int s0 = off[node];
    const int s1 = off[node + 1];

    float2 acc = make_float2(0.f, 0.f);
    if (h == 0) acc = bf16x2_to_f2(A2[((size_t)node << 5) + c]);   // self-loop once

    for (int p = s0; p < s1; p += 64) {
        int cnt = min(64, s1 - p);
        int idx = (l < cnt) ? csr[p + l] : 0;          // coalesced prefetch
        for (int j = 0; j < cnt; j += 8) {
#pragma unroll
            for (int k = 0; k < 4; k++) {
                int e = j + 4 * h + k;
                int src = __shfl(idx, min(e, 63));     // uniform control, all lanes
                if (e < cnt) {
                    float2 v = bf16x2_to_f2(A2[((size_t)src << 5) + c]);
                    acc.x += v.x;
                    acc.y += v.y;
                }
            }
        }
    }

    // combine half-waves: lane<32 += lane+32's acc
    float ox = __shfl(acc.x, c + 32);
    float oy = __shfl(acc.y, c + 32);
    if (h == 0) {
        acc.x += ox;
        acc.y += oy;
        *(float2*)(B + ((size_t)node << 6) + 2 * c) = acc;   // 256B coalesced
    }
}

extern "C" void kernel_launch(void* const* d_in, const int* in_sizes, int n_in,
                              void* d_out, int out_size, void* d_ws, size_t ws_size,
                              hipStream_t stream) {
    const float* x  = (const float*)d_in[0];
    const int*   ei = (const int*)d_in[1];
    const float* W1 = (const float*)d_in[2];
    const float* b1 = (const float*)d_in[3];
    const float* W2 = (const float*)d_in[4];
    const float* b2 = (const float*)d_in[5];
    const float* W3 = (const float*)d_in[6];
    const float* b3 = (const float*)d_in[7];
    float* out = (float*)d_out;

    const int N = in_sizes[0] / 64;    // 100000
    const int E = in_sizes[1] / 2;     // 1250000
    const int nbk = (N + BSIZE - 1) / BSIZE;        // 196 buckets

    // workspace layout
    int*   off  = (int*)d_ws;                       // N+1
    int*   csr  = off + (N + 1);                    // E
    int*   cur2 = csr + E;                          // 256
    int*   bbase= cur2 + 256;                       // 256
    uintptr_t pa = (uintptr_t)(bbase + 256);
    pa = (pa + 255) & ~(uintptr_t)255;
    float* dinv = (float*)pa;                       // N
    __hip_bfloat16* A = (__hip_bfloat16*)(dinv + N);// N*64 bf16 (hs)
    float* B    = (float*)(A + (size_t)N * 64);     // N*64 fp32 (agg)
    unsigned long long* pairs = (unsigned long long*)B;  // aliased: dead until agg1
                                                    // nbk*BCAP*8 = 12.9MB <= 25.6MB

    const int gG = (N + 63) / 64;
    const int gA = (N + 3) / 4;
    const int gP = (E + PCHUNK - 1) / PCHUNK;

    // CSR build (per call; ws re-poisoned every launch)
    bcur_init<<<1,   WG, 0, stream>>>(cur2, nbk);
    partition<<<gP,  WG, 0, stream>>>(ei, cur2, pairs, E);
    bsum_scan<<<1,   WG, 0, stream>>>(cur2, bbase, nbk, off, N);
    csr_local<<<nbk, 1024, 0, stream>>>(pairs, cur2, bbase, off, dinv, csr, N);

    // Layer 1: A = bf16(dinv.*(x@W1)); B = A[d] + sum A[src]
    gemm_fused<<<gG, WG, 0, stream>>>(x, W1, dinv, nullptr, 0, 1, nullptr, A, 1, N);
    aggregate <<<gA, WG, 0, stream>>>((const unsigned*)A, B, off, csr, N);

    // Layer 2: in = B (pre: relu(dinv*v + b1)); A = bf16(dinv.*(h@W2)); B = agg
    gemm_fused<<<gG, WG, 0, stream>>>(B, W2, dinv, b1, 1, 1, nullptr, A, 1, N);
    aggregate <<<gA, WG, 0, stream>>>((const unsigned*)A, B, off, csr, N);

    // Layer 3: in = B (pre: relu(dinv*v + b2)); out = h@W3 + b3 (fp32)
    gemm_fused<<<gG, WG, 0, stream>>>(B, W3, dinv, b2, 1, 0, b3, out, 0, N);
}